// Round 1
// baseline (225.775 us; speedup 1.0000x reference)
//
#include <hip/hip_runtime.h>
#include <cfloat>
#include <stdint.h>

// KmeansVectorQuantizer: B=8, T=2048, G=8, D=64, V=1024
// Outputs (flat f32): ids[B*T*G], quantized_st[B*T*G*D], kmeans, commit, total
#define G_ 8
#define D_ 64
#define V_ 1024
#define BT_ 16384
#define TPB_ 256
#define NSLOT_ 128            // spread loss-accumulator slots
#define TOKS_ 128             // tokens per scan block
#define NC_ 128               // codewords per chunk
#define NCHUNK_ (V_ / NC_)    // 8 chunks

typedef unsigned long long u64;
typedef uint32_t u32;
typedef _Float16 h8 __attribute__((ext_vector_type(8)));
typedef _Float16 h4 __attribute__((ext_vector_type(4)));
typedef float f32x4 __attribute__((ext_vector_type(4)));

// ws layout (bytes):
//   [0..511]    float part[128]     loss partial slots (memset 0)
//   [512..515]  int   cnt_active    (memset 0)
//   [1024)      float csqT[G_*V_]   32 KB  (transposed [g][v])
//   [33792)     int   list[BT_]     64 KB

// Fused prep: csq transpose, block-aggregated active compaction (1 atomic/block),
// and in-block coalesced zero-fill of padded tokens.
__global__ void prep_csq(const float* __restrict__ cb, const int* __restrict__ pad,
                         float* __restrict__ csqT,
                         int* __restrict__ cnt, int* __restrict__ list,
                         float* __restrict__ out_ids, float* __restrict__ out_q) {
    const int tid = threadIdx.x;
    const int idx = blockIdx.x * TPB_ + tid;     // < BT_ (exact grid)

    if (idx < V_ * G_) {
        const float4* r = (const float4*)(cb + (size_t)idx * D_);
        float s = 0.f;
#pragma unroll
        for (int i = 0; i < D_ / 4; ++i) {
            float4 c = r[i];
            s += c.x * c.x + c.y * c.y + c.z * c.z + c.w * c.w;
        }
        csqT[(idx & (G_ - 1)) * V_ + (idx >> 3)] = s;
    }

    __shared__ int s_cnt[8];          // [0..3] active per wave, [4..7] padded
    __shared__ int s_base, s_npl;
    __shared__ int s_plist[TPB_];     // block-local padded tokens
    const int lane = tid & 63, w = tid >> 6;
    const bool active = (pad[idx] == 0);
    u64 bal = __ballot(active);
    int na  = __popcll(bal);
    if (lane == 0) { s_cnt[w] = na; s_cnt[4 + w] = 64 - na; }
    __syncthreads();
    if (tid == 0) {
        int ta = s_cnt[0] + s_cnt[1] + s_cnt[2] + s_cnt[3];
        s_base = atomicAdd(cnt, ta);
        s_npl  = TPB_ - ta;
    }
    __syncthreads();
    int pre_a = 0, pre_p = 0;
    for (int i = 0; i < w; ++i) { pre_a += s_cnt[i]; pre_p += s_cnt[4 + i]; }
    const u64 mb = ((u64)1 << lane) - 1;
    if (active) list[s_base + pre_a + __popcll(bal & mb)] = idx;
    else        s_plist[pre_p + __popcll(~bal & mb)] = idx;
    __syncthreads();

    // coalesced zero-fill: one wave per padded token (2 KB contiguous)
    const int npl = s_npl;
    for (int i = w; i < npl; i += 4) {
        int tok = s_plist[i];
        float4 z = make_float4(0.f, 0.f, 0.f, 0.f);
        float4* q = (float4*)(out_q + (size_t)tok * (G_ * D_)) + lane * 2;
        q[0] = z;
        q[1] = z;
        if (lane < G_) out_ids[(size_t)tok * G_ + lane] = -1.0f;
    }
}

// MFMA scan: block = 128 tok x 1024 cw (one g). fp32 emulated as f16 hi/lo split
// (lo pre-scaled by 2^12 to dodge f16 denormals; separate cross accumulator,
// rescaled at the argmin fold). A (tokens) lives in registers; codebook chunks
// of 128 cw staged to LDS as f16 hi/lo, double-buffered, XOR-swizzled rows
// (byte ^= (row&7)<<4) so ds_read_b128 fragment reads are 2-way (free).
// Staging loads issue early / write late (latency hidden under MFMA).
__global__ __launch_bounds__(TPB_, 2) void vq_scan(
    const float* __restrict__ inp,
    const float* __restrict__ cb,
    const float* __restrict__ csqT,
    const int* __restrict__ cnt,
    const int* __restrict__ list,
    float* __restrict__ out_ids,
    float* __restrict__ out_q,
    float* __restrict__ part) {

    __shared__ __align__(16) unsigned char BH[2][NC_ * 128];  // 32 KB f16 hi
    __shared__ __align__(16) unsigned char BL[2][NC_ * 128];  // 32 KB f16 lo*2^12
    __shared__ float csq_s[V_];                               //  4 KB
    __shared__ u64 merge_s[2][TOKS_];                         //  2 KB

    const int nact = cnt[0];
    const int tile = blockIdx.x;
    if (tile * TOKS_ >= nact) return;          // uniform early-exit
    const int g   = blockIdx.y;
    const int tid = threadIdx.x;
    const int lane = tid & 63;
    const int w    = tid >> 6;
    const int mh   = w >> 1;                   // token half  (0..1)
    const int nh   = w & 1;                    // column half (0..1)
    const int r16  = lane & 15;
    const int kq   = lane >> 4;

    // csq stage
#pragma unroll
    for (int k = 0; k < 4; ++k)
        csq_s[k * 256 + tid] = csqT[g * V_ + k * 256 + tid];

    // ---- codebook chunk staging helpers ----
    // thread t owns float4 f = (h*4+ii)*256 + t : row = f>>4, dq = f&15
    const int sdq = tid & 15;
    const int srB = tid >> 4;

    auto stage_issue = [&](int c, int h, float4* pf) {
#pragma unroll
        for (int ii = 0; ii < 4; ++ii) {
            int r = (h * 4 + ii) * 16 + srB;
            pf[ii] = *(const float4*)(cb +
                       (size_t)((c * NC_ + r) * G_ + g) * D_ + sdq * 4);
        }
    };
    auto stage_write = [&](int nb, int h, const float4* pf) {
#pragma unroll
        for (int ii = 0; ii < 4; ++ii) {
            int r = (h * 4 + ii) * 16 + srB;
            u32 sw = (u32)((r & 7) << 4);
            u32 bo = (u32)(r * 128 + sdq * 8);
            float xs[4] = {pf[ii].x, pf[ii].y, pf[ii].z, pf[ii].w};
            h4 hv, lv;
#pragma unroll
            for (int e = 0; e < 4; ++e) {
                _Float16 hh = (_Float16)xs[e];
                hv[e] = hh;
                lv[e] = (_Float16)((xs[e] - (float)hh) * 4096.f);
            }
            *(h4*)(&BH[nb][bo ^ sw]) = hv;
            *(h4*)(&BL[nb][bo ^ sw]) = lv;
        }
    };

    // ---- prologue: issue chunk-0 staging, build A fragments, write, barrier --
    float4 s0[4], s1[4];
    stage_issue(0, 0, s0);
    stage_issue(0, 1, s1);

    // A fragments: lane supplies x[row = l&15][k = (l>>4)*8 + e] per kfrag.
    h8 AH[4][2], AL[4][2];
#pragma unroll
    for (int rf = 0; rf < 4; ++rf) {
        int p = tile * TOKS_ + mh * 64 + rf * 16 + r16;
        int tok = list[p < nact ? p : 0];
        const float* xr = inp + (size_t)tok * (G_ * D_) + g * D_;
#pragma unroll
        for (int kf = 0; kf < 2; ++kf) {
            const float4* xp = (const float4*)(xr + kf * 32 + kq * 8);
            float4 a = xp[0], b = xp[1];
            float xs[8] = {a.x, a.y, a.z, a.w, b.x, b.y, b.z, b.w};
#pragma unroll
            for (int e = 0; e < 8; ++e) {
                _Float16 hh = (_Float16)xs[e];
                AH[rf][kf][e] = hh;
                AL[rf][kf][e] = (_Float16)((xs[e] - (float)hh) * 4096.f);
            }
        }
    }

    stage_write(0, 0, s0);
    stage_write(0, 1, s1);
    __syncthreads();

    // ---- main chunk loop ----
    float bestd[16];
    int   bestid[16];
#pragma unroll
    for (int s = 0; s < 16; ++s) { bestd[s] = FLT_MAX; bestid[s] = 0; }

    const u32 swB = (u32)((r16 & 7) << 4);
    const u32 boB = (u32)((nh * 64 + r16) * 128 + kq * 16);

    auto compute_cf = [&](int c, int cur, int cf) {
        u32 ob = boB + (u32)(cf * 2048);
        const h8 bh0 = *(const h8*)(&BH[cur][(ob +  0) ^ swB]);
        const h8 bh1 = *(const h8*)(&BH[cur][(ob + 64) ^ swB]);
        const h8 bl0 = *(const h8*)(&BL[cur][(ob +  0) ^ swB]);
        const h8 bl1 = *(const h8*)(&BL[cur][(ob + 64) ^ swB]);
        f32x4 t[4], tc[4];
#pragma unroll
        for (int rf = 0; rf < 4; ++rf) {
            f32x4 a  = {0.f, 0.f, 0.f, 0.f};
            f32x4 ac = {0.f, 0.f, 0.f, 0.f};
            a  = __builtin_amdgcn_mfma_f32_16x16x32_f16(AH[rf][0], bh0, a,  0, 0, 0);
            a  = __builtin_amdgcn_mfma_f32_16x16x32_f16(AH[rf][1], bh1, a,  0, 0, 0);
            ac = __builtin_amdgcn_mfma_f32_16x16x32_f16(AH[rf][0], bl0, ac, 0, 0, 0);
            ac = __builtin_amdgcn_mfma_f32_16x16x32_f16(AH[rf][1], bl1, ac, 0, 0, 0);
            ac = __builtin_amdgcn_mfma_f32_16x16x32_f16(AL[rf][0], bh0, ac, 0, 0, 0);
            ac = __builtin_amdgcn_mfma_f32_16x16x32_f16(AL[rf][1], bh1, ac, 0, 0, 0);
            t[rf] = a; tc[rf] = ac;
        }
        const int vcol = c * NC_ + nh * 64 + cf * 16 + r16;
        const float cq = csq_s[vcol];
#pragma unroll
        for (int rf = 0; rf < 4; ++rf)
#pragma unroll
            for (int q = 0; q < 4; ++q) {
                float d = fmaf(-2.f, t[rf][q], cq);
                d = fmaf(-0x1.0p-11f, tc[rf][q], d);   // -2 * 2^-12 (lo rescale)
                int s = rf * 4 + q;
                if (d < bestd[s]) { bestd[s] = d; bestid[s] = vcol; }
            }
    };

#pragma unroll 2
    for (int c = 0; c < NCHUNK_; ++c) {
        const int cur = c & 1, nb = cur ^ 1;
        float4 pf0[4], pf1[4];
        if (c < NCHUNK_ - 1) stage_issue(c + 1, 0, pf0);

        compute_cf(c, cur, 0);
        compute_cf(c, cur, 1);

        if (c < NCHUNK_ - 1) { stage_write(nb, 0, pf0); stage_issue(c + 1, 1, pf1); }

        compute_cf(c, cur, 2);
        compute_cf(c, cur, 3);

        if (c < NCHUNK_ - 1) stage_write(nb, 1, pf1);
        __syncthreads();
    }

    // ---- cross-lane argmin (16-lane butterfly) + cross-wave-pair merge ----
#pragma unroll
    for (int s = 0; s < 16; ++s) {
        u32 u = __float_as_uint(bestd[s]);
        u = u ^ ((u >> 31) ? 0xFFFFFFFFu : 0x80000000u);   // sortable float
        u64 pk = ((u64)u << 32) | (u32)bestid[s];
#pragma unroll
        for (int off = 1; off <= 8; off <<= 1) {
            u64 o = __shfl_xor(pk, off, 64);
            pk = (o < pk) ? o : pk;
        }
        if (r16 == 0) {
            int row = mh * 64 + (s >> 2) * 16 + kq * 4 + (s & 3);
            merge_s[nh][row] = pk;
        }
    }
    __syncthreads();

    // ---- fused epilogue: ids, quantized, loss (2 threads per token) ----
    float l = 0.f;
    {
        int tl = tid >> 1, qv = tid & 1;
        int p  = tile * TOKS_ + tl;
        if (p < nact) {
            int tok = list[p];
            u64 qa = merge_s[0][tl], qb = merge_s[1][tl];
            u64 qm = (qb < qa) ? qb : qa;
            int id  = (int)(qm & 0xFFFFFFFFull);
            const float4* cr = (const float4*)(cb + ((size_t)id * G_ + g) * D_) + qv * 8;
            const float4* xr = (const float4*)(inp + (size_t)tok * (G_ * D_) + g * D_) + qv * 8;
            float4* qo = (float4*)(out_q + (size_t)tok * (G_ * D_) + g * D_) + qv * 8;
#pragma unroll
            for (int k = 0; k < 8; ++k) {
                float4 cc = cr[k], xx = xr[k];
                float dx = cc.x - xx.x, dy = cc.y - xx.y;
                float dz = cc.z - xx.z, dw = cc.w - xx.w;
                l += dx * dx + dy * dy + dz * dz + dw * dw;
                qo[k] = cc;
            }
            if (qv == 0) out_ids[(size_t)tok * G_ + g] = (float)id;
        }
    }
#pragma unroll
    for (int off = 32; off > 0; off >>= 1) l += __shfl_down(l, off, 64);
    if (lane == 0) {
        int slot = ((blockIdx.y * gridDim.x + blockIdx.x) * 4 + w) & (NSLOT_ - 1);
        atomicAdd(&part[slot], l);
    }
}

__global__ void finalize_kernel(const float* __restrict__ part,
                                const int* __restrict__ cnt,
                                float* __restrict__ out_losses) {
    int lane = threadIdx.x;                    // one wave of 64
    float l = part[lane] + part[lane + 64];
#pragma unroll
    for (int off = 32; off > 0; off >>= 1) l += __shfl_down(l, off, 64);
    if (lane == 0) {
        float k = l / (float)cnt[0];
        out_losses[0] = k;        // kmeans_loss
        out_losses[1] = k;        // commitment_loss (numerically identical)
        out_losses[2] = 2.f * k;  // total (BETA=1)
    }
}

extern "C" void kernel_launch(void* const* d_in, const int* in_sizes, int n_in,
                              void* d_out, int out_size, void* d_ws, size_t ws_size,
                              hipStream_t stream) {
    const float* inp = (const float*)d_in[0];   // (8,2048,512) f32
    const int*   pad = (const int*)d_in[1];     // (8,2048) i32
    const float* cb  = (const float*)d_in[2];   // (1024,8,64) f32

    float* out   = (float*)d_out;
    float* o_ids = out;                              // B*T*G
    float* o_q   = out + (size_t)BT_ * G_;           // B*T*G*D
    float* o_ls  = o_q + (size_t)BT_ * G_ * D_;      // 3 scalars

    float* part  = (float*)d_ws;
    int*   cnt   = (int*)((char*)d_ws + 512);
    float* csqT  = (float*)((char*)d_ws + 1024);
    int*   list  = (int*)((char*)d_ws + 33792);

    hipMemsetAsync(d_ws, 0, 1024, stream);

    prep_csq<<<dim3(BT_ / TPB_), dim3(TPB_), 0, stream>>>(
        cb, pad, csqT, cnt, list, o_ids, o_q);

    dim3 grid(BT_ / TOKS_, G_);                // worst-case 128-token tiles x g
    vq_scan<<<grid, dim3(TPB_), 0, stream>>>(
        inp, cb, csqT, cnt, list, o_ids, o_q, part);

    finalize_kernel<<<1, dim3(64), 0, stream>>>(part, cnt, o_ls);
}

// Round 2
// 135.255 us; speedup vs baseline: 1.6693x; 1.6693x over previous
//
#include <hip/hip_runtime.h>
#include <cfloat>
#include <stdint.h>

// KmeansVectorQuantizer: B=8, T=2048, G=8, D=64, V=1024
// Outputs (flat f32): ids[B*T*G], quantized_st[B*T*G*D], kmeans, commit, total
#define G_ 8
#define D_ 64
#define V_ 1024
#define BT_ 16384
#define TPB_ 256
#define NSLOT_ 128            // spread loss-accumulator slots
#define TOKS_ 128             // tokens per scan block
#define NC_ 128               // codewords per chunk
#define NCHUNK_ (V_ / NC_)    // 8 chunks

typedef unsigned long long u64;
typedef uint32_t u32;
typedef _Float16 h8 __attribute__((ext_vector_type(8)));
typedef _Float16 h4 __attribute__((ext_vector_type(4)));
typedef float f32x4 __attribute__((ext_vector_type(4)));

typedef __attribute__((address_space(3))) uint32_t lds_u32;
typedef __attribute__((address_space(1))) uint32_t glb_u32;

// global->LDS DMA, 16B per lane; LDS dest = uniform base + lane*16
#define GL2LDS(gsrc, ldst) \
    __builtin_amdgcn_global_load_lds((glb_u32*)(gsrc), (lds_u32*)(ldst), 16, 0, 0)

// ws layout (bytes):
//   [0..511]     float part[128]        loss partial slots (memset 0)
//   [512..515]   int   cnt_active       (memset 0)
//   [1024)       float csqT[G_*V_]      32 KB  (transposed [g][v])
//   [33792)      int   list[BT_]        64 KB
//   [131072)     f16   cbH[V_*G_*64]    1 MB   codebook hi  (natural [v][g][d])
//   [1179648)    f16   cbL[V_*G_*64]    1 MB   codebook (lo*2^12)

// Fused prep: csq transpose, f32->f16 hi/lo codebook split, block-aggregated
// active compaction (1 atomic/block), coalesced zero-fill of padded tokens.
__global__ void prep_csq(const float* __restrict__ cb, const int* __restrict__ pad,
                         float* __restrict__ csqT,
                         int* __restrict__ cnt, int* __restrict__ list,
                         float* __restrict__ out_ids, float* __restrict__ out_q,
                         _Float16* __restrict__ cbH, _Float16* __restrict__ cbL) {
    const int tid = threadIdx.x;
    const int idx = blockIdx.x * TPB_ + tid;     // < BT_ (exact grid)

    if (idx < V_ * G_) {
        const float4* r = (const float4*)(cb + (size_t)idx * D_);
        _Float16* hp = cbH + (size_t)idx * 64;
        _Float16* lp = cbL + (size_t)idx * 64;
        float s = 0.f;
#pragma unroll
        for (int i = 0; i < D_ / 4; ++i) {
            float4 c = r[i];
            s += c.x * c.x + c.y * c.y + c.z * c.z + c.w * c.w;
            float xs[4] = {c.x, c.y, c.z, c.w};
            h4 hv, lv;
#pragma unroll
            for (int e = 0; e < 4; ++e) {
                _Float16 hh = (_Float16)xs[e];
                hv[e] = hh;
                lv[e] = (_Float16)((xs[e] - (float)hh) * 4096.f);
            }
            *(h4*)(hp + i * 4) = hv;
            *(h4*)(lp + i * 4) = lv;
        }
        csqT[(idx & (G_ - 1)) * V_ + (idx >> 3)] = s;
    }

    __shared__ int s_cnt[8];          // [0..3] active per wave, [4..7] padded
    __shared__ int s_base, s_npl;
    __shared__ int s_plist[TPB_];     // block-local padded tokens
    const int lane = tid & 63, w = tid >> 6;
    const bool active = (pad[idx] == 0);
    u64 bal = __ballot(active);
    int na  = __popcll(bal);
    if (lane == 0) { s_cnt[w] = na; s_cnt[4 + w] = 64 - na; }
    __syncthreads();
    if (tid == 0) {
        int ta = s_cnt[0] + s_cnt[1] + s_cnt[2] + s_cnt[3];
        s_base = atomicAdd(cnt, ta);
        s_npl  = TPB_ - ta;
    }
    __syncthreads();
    int pre_a = 0, pre_p = 0;
    for (int i = 0; i < w; ++i) { pre_a += s_cnt[i]; pre_p += s_cnt[4 + i]; }
    const u64 mb = ((u64)1 << lane) - 1;
    if (active) list[s_base + pre_a + __popcll(bal & mb)] = idx;
    else        s_plist[pre_p + __popcll(~bal & mb)] = idx;
    __syncthreads();

    // coalesced zero-fill: one wave per padded token (2 KB contiguous)
    const int npl = s_npl;
    for (int i = w; i < npl; i += 4) {
        int tok = s_plist[i];
        float4 z = make_float4(0.f, 0.f, 0.f, 0.f);
        float4* q = (float4*)(out_q + (size_t)tok * (G_ * D_)) + lane * 2;
        q[0] = z;
        q[1] = z;
        if (lane < G_) out_ids[(size_t)tok * G_ + lane] = -1.0f;
    }
}

// MFMA scan: block = 128 tok x 1024 cw (one g). fp32 emulated as f16 hi/lo
// split (lo pre-scaled 2^12; separate cross accumulator rescaled at the fold).
// A (tokens) in registers; codebook chunks DMA'd to LDS via global_load_lds
// from the pre-split f16 arrays (zero staging VGPRs, zero conversion VALU).
// LDS image is XOR-swizzled (byte ^= (row&7)<<4) by inverse-swizzling the
// per-lane GLOBAL source block (linear LDS dest) -> ds_read_b128 is 2-way
// (measured 0 conflicts in R1). One barrier per chunk; next chunk's 8 DMA
// loads issued at phase top, landing under ~780 MFMAs of compute.
__global__ __launch_bounds__(TPB_, 2) void vq_scan(
    const float* __restrict__ inp,
    const float* __restrict__ cb,
    const float* __restrict__ csqT,
    const int* __restrict__ cnt,
    const int* __restrict__ list,
    const _Float16* __restrict__ cbH,
    const _Float16* __restrict__ cbL,
    float* __restrict__ out_ids,
    float* __restrict__ out_q,
    float* __restrict__ part) {

    __shared__ __align__(16) unsigned char BH[2][NC_ * 128];  // 32 KB f16 hi
    __shared__ __align__(16) unsigned char BL[2][NC_ * 128];  // 32 KB f16 lo
    __shared__ float csq_s[V_];                               //  4 KB
    __shared__ u64 merge_s[2][TOKS_];                         //  2 KB

    const int nact = cnt[0];
    const int tile = blockIdx.x;
    if (tile * TOKS_ >= nact) return;          // uniform early-exit
    const int g   = blockIdx.y;
    const int tid = threadIdx.x;
    const int lane = tid & 63;
    const int w    = tid >> 6;
    const int mh   = w >> 1;                   // token half  (0..1)
    const int nh   = w & 1;                    // column half (0..1)
    const int r16  = lane & 15;
    const int kq   = lane >> 4;

    // csq stage
#pragma unroll
    for (int k = 0; k < 4; ++k)
        csq_s[k * 256 + tid] = csqT[g * V_ + k * 256 + tid];

    // per-lane DMA source base: LDS linear pos L = w*4096 + i*1024 + lane*16
    // -> row = w*32 + i*8 + (lane>>3), blk = lane&7; want LDS[row][blk] =
    // logical[row][blk ^ (row&7)]  (row&7 == lane>>3 here)
    const size_t srcoff = (size_t)(w * 32 + (lane >> 3)) * 1024 + (size_t)g * 128
                        + (size_t)(((lane & 7) ^ (lane >> 3)) * 16);
    const unsigned char* sH = (const unsigned char*)cbH + srcoff;
    const unsigned char* sL = (const unsigned char*)cbL + srcoff;
    const int ldsb = w * 4096;                 // wave's slice of each buffer

    // issue chunk-0 staging (lands during A-fragment build)
#pragma unroll
    for (int i = 0; i < 4; ++i) GL2LDS(sH + i * 8192, &BH[0][ldsb + i * 1024]);
#pragma unroll
    for (int i = 0; i < 4; ++i) GL2LDS(sL + i * 8192, &BL[0][ldsb + i * 1024]);

    // A fragments: lane supplies x[row = l&15][k = (l>>4)*8 + e] per kfrag
    h8 AH[4][2], AL[4][2];
#pragma unroll
    for (int rf = 0; rf < 4; ++rf) {
        int p = tile * TOKS_ + mh * 64 + rf * 16 + r16;
        int tok = list[p < nact ? p : 0];
        const float* xr = inp + (size_t)tok * (G_ * D_) + g * D_;
#pragma unroll
        for (int kf = 0; kf < 2; ++kf) {
            const float4* xp = (const float4*)(xr + kf * 32 + kq * 8);
            float4 a = xp[0], b = xp[1];
            float xs[8] = {a.x, a.y, a.z, a.w, b.x, b.y, b.z, b.w};
#pragma unroll
            for (int e = 0; e < 8; ++e) {
                _Float16 hh = (_Float16)xs[e];
                AH[rf][kf][e] = hh;
                AL[rf][kf][e] = (_Float16)((xs[e] - (float)hh) * 4096.f);
            }
        }
    }

    float bestd[16];
    int   bestid[16];
#pragma unroll
    for (int s = 0; s < 16; ++s) { bestd[s] = FLT_MAX; bestid[s] = 0; }

    __syncthreads();                           // drains vmcnt: chunk 0 ready

    const u32 swB = (u32)((r16 & 7) << 4);
    const u32 boB = (u32)((nh * 64 + r16) * 128 + kq * 16);

    for (int c = 0; c < NCHUNK_; ++c) {
        const int cur = c & 1;
        const unsigned char* BHc = &BH[0][0] + cur * (NC_ * 128);
        const unsigned char* BLc = &BL[0][0] + cur * (NC_ * 128);

        if (c < NCHUNK_ - 1) {                 // issue next chunk's DMA now
            unsigned char* dH = &BH[0][0] + (cur ^ 1) * (NC_ * 128) + ldsb;
            unsigned char* dL = &BL[0][0] + (cur ^ 1) * (NC_ * 128) + ldsb;
            const unsigned char* nH = sH + (size_t)(c + 1) * 131072;
            const unsigned char* nL = sL + (size_t)(c + 1) * 131072;
#pragma unroll
            for (int i = 0; i < 4; ++i) GL2LDS(nH + i * 8192, dH + i * 1024);
#pragma unroll
            for (int i = 0; i < 4; ++i) GL2LDS(nL + i * 8192, dL + i * 1024);
        }

#pragma unroll 1
        for (int cf = 0; cf < 4; ++cf) {
            const u32 ob = boB + (u32)(cf * 2048);
            const h8 bh0 = *(const h8*)(BHc + ((ob)      ^ swB));
            const h8 bh1 = *(const h8*)(BHc + ((ob + 64) ^ swB));
            const h8 bl0 = *(const h8*)(BLc + ((ob)      ^ swB));
            const h8 bl1 = *(const h8*)(BLc + ((ob + 64) ^ swB));
            const int vcol = c * NC_ + nh * 64 + cf * 16 + r16;
            const float cq = csq_s[vcol];
#pragma unroll
            for (int rf = 0; rf < 4; ++rf) {
                f32x4 a  = {0.f, 0.f, 0.f, 0.f};
                f32x4 ac = {0.f, 0.f, 0.f, 0.f};
                a  = __builtin_amdgcn_mfma_f32_16x16x32_f16(AH[rf][0], bh0, a,  0, 0, 0);
                a  = __builtin_amdgcn_mfma_f32_16x16x32_f16(AH[rf][1], bh1, a,  0, 0, 0);
                ac = __builtin_amdgcn_mfma_f32_16x16x32_f16(AH[rf][0], bl0, ac, 0, 0, 0);
                ac = __builtin_amdgcn_mfma_f32_16x16x32_f16(AH[rf][1], bl1, ac, 0, 0, 0);
                ac = __builtin_amdgcn_mfma_f32_16x16x32_f16(AL[rf][0], bh0, ac, 0, 0, 0);
                ac = __builtin_amdgcn_mfma_f32_16x16x32_f16(AL[rf][1], bh1, ac, 0, 0, 0);
#pragma unroll
                for (int q = 0; q < 4; ++q) {
                    float d = fmaf(-2.f, a[q], cq);
                    d = fmaf(-0x1.0p-11f, ac[q], d);   // -2 * 2^-12 (lo rescale)
                    int s = rf * 4 + q;
                    if (d < bestd[s]) { bestd[s] = d; bestid[s] = vcol; }
                }
            }
        }
        __syncthreads();   // all waves done reading cur; next chunk DMA drained
    }

    // ---- cross-lane argmin (16-lane butterfly) + cross-wave-pair merge ----
#pragma unroll
    for (int s = 0; s < 16; ++s) {
        u32 u = __float_as_uint(bestd[s]);
        u = u ^ ((u >> 31) ? 0xFFFFFFFFu : 0x80000000u);   // sortable float
        u64 pk = ((u64)u << 32) | (u32)bestid[s];
#pragma unroll
        for (int off = 1; off <= 8; off <<= 1) {
            u64 o = __shfl_xor(pk, off, 64);
            pk = (o < pk) ? o : pk;
        }
        if (r16 == 0) {
            int row = mh * 64 + (s >> 2) * 16 + kq * 4 + (s & 3);
            merge_s[nh][row] = pk;
        }
    }
    __syncthreads();

    // ---- fused epilogue: ids, quantized, loss (2 threads per token) ----
    float l = 0.f;
    {
        int tl = tid >> 1, qv = tid & 1;
        int p  = tile * TOKS_ + tl;
        if (p < nact) {
            int tok = list[p];
            u64 qa = merge_s[0][tl], qb = merge_s[1][tl];
            u64 qm = (qb < qa) ? qb : qa;
            int id  = (int)(qm & 0xFFFFFFFFull);
            const float4* cr = (const float4*)(cb + ((size_t)id * G_ + g) * D_) + qv * 8;
            const float4* xr = (const float4*)(inp + (size_t)tok * (G_ * D_) + g * D_) + qv * 8;
            float4* qo = (float4*)(out_q + (size_t)tok * (G_ * D_) + g * D_) + qv * 8;
#pragma unroll
            for (int k = 0; k < 8; ++k) {
                float4 cc = cr[k], xx = xr[k];
                float dx = cc.x - xx.x, dy = cc.y - xx.y;
                float dz = cc.z - xx.z, dw = cc.w - xx.w;
                l += dx * dx + dy * dy + dz * dz + dw * dw;
                qo[k] = cc;
            }
            if (qv == 0) out_ids[(size_t)tok * G_ + g] = (float)id;
        }
    }
#pragma unroll
    for (int off = 32; off > 0; off >>= 1) l += __shfl_down(l, off, 64);
    if (lane == 0) {
        int slot = ((blockIdx.y * gridDim.x + blockIdx.x) * 4 + w) & (NSLOT_ - 1);
        atomicAdd(&part[slot], l);
    }
}

__global__ void finalize_kernel(const float* __restrict__ part,
                                const int* __restrict__ cnt,
                                float* __restrict__ out_losses) {
    int lane = threadIdx.x;                    // one wave of 64
    float l = part[lane] + part[lane + 64];
#pragma unroll
    for (int off = 32; off > 0; off >>= 1) l += __shfl_down(l, off, 64);
    if (lane == 0) {
        float k = l / (float)cnt[0];
        out_losses[0] = k;        // kmeans_loss
        out_losses[1] = k;        // commitment_loss (numerically identical)
        out_losses[2] = 2.f * k;  // total (BETA=1)
    }
}

extern "C" void kernel_launch(void* const* d_in, const int* in_sizes, int n_in,
                              void* d_out, int out_size, void* d_ws, size_t ws_size,
                              hipStream_t stream) {
    const float* inp = (const float*)d_in[0];   // (8,2048,512) f32
    const int*   pad = (const int*)d_in[1];     // (8,2048) i32
    const float* cb  = (const float*)d_in[2];   // (1024,8,64) f32

    float* out   = (float*)d_out;
    float* o_ids = out;                              // B*T*G
    float* o_q   = out + (size_t)BT_ * G_;           // B*T*G*D
    float* o_ls  = o_q + (size_t)BT_ * G_ * D_;      // 3 scalars

    float*     part = (float*)d_ws;
    int*       cnt  = (int*)((char*)d_ws + 512);
    float*     csqT = (float*)((char*)d_ws + 1024);
    int*       list = (int*)((char*)d_ws + 33792);
    _Float16*  cbH  = (_Float16*)((char*)d_ws + 131072);
    _Float16*  cbL  = (_Float16*)((char*)d_ws + 131072 + 1048576);

    hipMemsetAsync(d_ws, 0, 1024, stream);

    prep_csq<<<dim3(BT_ / TPB_), dim3(TPB_), 0, stream>>>(
        cb, pad, csqT, cnt, list, o_ids, o_q, cbH, cbL);

    dim3 grid(BT_ / TOKS_, G_);                // worst-case 128-token tiles x g
    vq_scan<<<grid, dim3(TPB_), 0, stream>>>(
        inp, cb, csqT, cnt, list, cbH, cbL, o_ids, o_q, part);

    finalize_kernel<<<1, dim3(64), 0, stream>>>(part, cnt, o_ls);
}